// Round 3
// baseline (2182.973 us; speedup 1.0000x reference)
//
#include <hip/hip_runtime.h>
#include <math.h>

#define NN 10000
#define NE 40000
#define NGRAPH 64
#define HID 64
#define EDIM 16
#define NLAYERS 3

// ---- fused message kernel geometry ----
#define GNODES 16
#define NGROUPS (NN / GNODES)       // 625
#define OSUB 32                     // o-slice per block (2 slices)
#define MSG_THREADS 1024
#define B_FLOATS (GNODES * 64 * OSUB)  // 32768 floats = 128 KB
#define HS_FLOATS (64 * GNODES)        // 1024 floats
#define MSG_LDS_FLOATS (B_FLOATS + HS_FLOATS)

__device__ __forceinline__ float silu_f(float x) { return x / (1.f + expf(-x)); }

// ---------------- small row GEMM: out[M][64] = act(A[M][K] @ W[K][64] + bias) ----
template<int K, bool DO_SILU, bool HAS_BIAS>
__global__ __launch_bounds__(256)
void k_rowmm(const float* __restrict__ A, const float* __restrict__ W,
             const float* __restrict__ bias, float* __restrict__ out, int M) {
    __shared__ float Ws[K * 64];
    __shared__ float As[4 * K];
    const int tid = threadIdx.x;
    for (int idx = tid; idx < K * 64; idx += 256) Ws[idx] = W[idx];
    const int r0 = blockIdx.x * 4;
    for (int idx = tid; idx < 4 * K; idx += 256) {
        int r = r0 + idx / K;
        As[idx] = (r < M) ? A[(size_t)r * K + (idx % K)] : 0.f;
    }
    __syncthreads();
    const int rr = tid >> 6, c = tid & 63;
    const int r = r0 + rr;
    if (r >= M) return;
    float s = HAS_BIAS ? bias[c] : 0.f;
#pragma unroll
    for (int k = 0; k < K; k++) s += As[rr * K + k] * Ws[k * 64 + c];
    if (DO_SILU) s = silu_f(s);
    out[(size_t)r * 64 + c] = s;
}

// ---------------- degree histograms (src + dst) ----------------
__global__ void k_hist(const int* __restrict__ ei, int* __restrict__ cnt_s,
                       int* __restrict__ cnt_d) {
    int e = blockIdx.x * 256 + threadIdx.x;
    if (e >= NE) return;
    atomicAdd(&cnt_s[ei[e]], 1);
    atomicAdd(&cnt_d[ei[NE + e]], 1);
}

__global__ void k_invdeg(const int* __restrict__ cnt_d, float* __restrict__ invd) {
    int n = blockIdx.x * 256 + threadIdx.x;
    if (n < NN) {
        int d = cnt_d[n];
        invd[n] = (d > 0) ? 1.f / (float)d : 0.f;
    }
}

// ---------------- single-block exclusive scan over NN counts ----------------
__global__ __launch_bounds__(1024)
void k_scan(const int* __restrict__ cnt, int* __restrict__ off, int* __restrict__ cur) {
    __shared__ int part[1024];
    const int t = threadIdx.x;
    const int CH = (NN + 1023) / 1024;  // 10
    const int base0 = t * CH;
    int s = 0;
    for (int i = 0; i < CH; i++) {
        int idx = base0 + i;
        if (idx < NN) s += cnt[idx];
    }
    part[t] = s;
    __syncthreads();
    for (int d = 1; d < 1024; d <<= 1) {
        int v = (t >= d) ? part[t - d] : 0;
        __syncthreads();
        part[t] += v;
        __syncthreads();
    }
    int run = (t == 0) ? 0 : part[t - 1];
    for (int i = 0; i < CH; i++) {
        int idx = base0 + i;
        if (idx < NN) {
            off[idx] = run;
            run += cnt[idx];
            cur[idx] = 0;
        }
    }
    if (t == 1023) off[NN] = run;
}

__global__ void k_fill(const int* __restrict__ keys, const int* __restrict__ off,
                       int* __restrict__ cur, int* __restrict__ eid) {
    int e = blockIdx.x * 256 + threadIdx.x;
    if (e >= NE) return;
    int s = keys[e];
    int p = atomicAdd(&cur[s], 1);
    eid[off[s] + p] = e;
}

// ---------------- fused B-compute + message store (v3: no atomics) ----------------
// Block = (group of 16 src nodes) x (o-slice of 32). B[j,k,o] in LDS (swizzled),
// msg[e, o-slice] = C[src, o-slice] + sum_k g[e,k]*B[src,k,o] stored coalesced.
__global__ __launch_bounds__(MSG_THREADS)
void k_msg(const float* __restrict__ h, const float* __restrict__ g,
           const float* __restrict__ w2, const float* __restrict__ Cbuf,
           const int* __restrict__ csr_off, const int* __restrict__ csr_eid,
           float* __restrict__ msg) {
    extern __shared__ float lds[];
    float* Bl  = lds;               // [16][64][32] swizzled (see below)
    float* h_s = lds + B_FLOATS;    // [64][16]: h_s[i*16+j] = h[n0+j][i]
    __shared__ int offs[GNODES + 1];

    const int tid   = threadIdx.x;
    const int slice = blockIdx.x & 1;
    const int grp   = blockIdx.x >> 1;
    const int o0    = slice * OSUB;
    const int n0    = grp * GNODES;

    // stage h (transposed) + csr offsets
    h_s[tid] = h[(size_t)(n0 + (tid & 15)) * 64 + (tid >> 4)];
    if (tid <= GNODES) offs[tid] = csr_off[n0 + tid];
    __syncthreads();

    // ---- B compute: thread (o = tid&31, kq = tid>>5) does k in {kq, kq+32}, all 16 j
    const int o  = tid & 31;
    const int kq = tid >> 5;
    const float* w2a = w2 + (size_t)kq * 4096 + o0 + o;
    const float* w2b = w2 + (size_t)(kq + 32) * 4096 + o0 + o;

    float acc0[16], acc1[16];
#pragma unroll
    for (int j = 0; j < 16; ++j) { acc0[j] = 0.f; acc1[j] = 0.f; }

#pragma unroll 4
    for (int i = 0; i < 64; ++i) {
        const float wa = w2a[i * 64];
        const float wb = w2b[i * 64];
        const float4 h0 = *(const float4*)(h_s + i * 16);
        const float4 h1 = *(const float4*)(h_s + i * 16 + 4);
        const float4 h2 = *(const float4*)(h_s + i * 16 + 8);
        const float4 h3 = *(const float4*)(h_s + i * 16 + 12);
#define ACC16(A, WV) \
        A[0]  += (WV) * h0.x; A[1]  += (WV) * h0.y; A[2]  += (WV) * h0.z; A[3]  += (WV) * h0.w; \
        A[4]  += (WV) * h1.x; A[5]  += (WV) * h1.y; A[6]  += (WV) * h1.z; A[7]  += (WV) * h1.w; \
        A[8]  += (WV) * h2.x; A[9]  += (WV) * h2.y; A[10] += (WV) * h2.z; A[11] += (WV) * h2.w; \
        A[12] += (WV) * h3.x; A[13] += (WV) * h3.y; A[14] += (WV) * h3.z; A[15] += (WV) * h3.w;
        ACC16(acc0, wa)
        ACC16(acc1, wb)
#undef ACC16
    }
    // write B swizzled: element (j,k,o) at j*2048 + k*32 + ((o>>2)^(k&7))*4 + (o&3)
    {
        const int oq = o >> 2, ol = o & 3;
        const int g0 = ((oq ^ (kq & 7)) << 2) + ol;
        const int g1 = ((oq ^ ((kq + 32) & 7)) << 2) + ol;
#pragma unroll
        for (int j = 0; j < 16; ++j) {
            Bl[j * 2048 + kq * 32 + g0]        = acc0[j];
            Bl[j * 2048 + (kq + 32) * 32 + g1] = acc1[j];
        }
    }
    __syncthreads();

    // ---- edge phase: task = (edge slot) x (o-quad of 4) ----
    const int P0 = offs[0];
    const int Etot = offs[GNODES] - P0;
    const int ntask = Etot * 8;
    for (int t = tid; t < ntask; t += MSG_THREADS) {
        const int slot = t >> 3, o4 = t & 7;
        const int gpos = P0 + slot;
        int j = 0;
#pragma unroll
        for (int q = 1; q < GNODES; ++q) j += (gpos >= offs[q]) ? 1 : 0;
        const int e = csr_eid[gpos];
        const float* grow = g + (size_t)e * 64;
        const float* Bj = Bl + j * 2048;

        const float4 c4 = *(const float4*)(Cbuf + (size_t)(n0 + j) * 64 + o0 + o4 * 4);
        float m0 = c4.x, m1 = c4.y, m2 = c4.z, m3 = c4.w;
#pragma unroll
        for (int k8 = 0; k8 < 8; ++k8) {
            const float4 ga = *(const float4*)(grow + k8 * 8);
            const float4 gb = *(const float4*)(grow + k8 * 8 + 4);
            const float gv[8] = {ga.x, ga.y, ga.z, ga.w, gb.x, gb.y, gb.z, gb.w};
#pragma unroll
            for (int kk = 0; kk < 8; ++kk) {
                const int k = k8 * 8 + kk;
                const float4 b4 = *(const float4*)(Bj + k * 32 + ((o4 ^ (k & 7)) << 2));
                m0 += gv[kk] * b4.x;
                m1 += gv[kk] * b4.y;
                m2 += gv[kk] * b4.z;
                m3 += gv[kk] * b4.w;
            }
        }
        *(float4*)(msg + (size_t)e * 64 + o0 + o4 * 4) = make_float4(m0, m1, m2, m3);
    }
}

// ---------------- gather by dst + root GEMM + silu (replaces atomics+k_final) ----
__global__ __launch_bounds__(256)
void k_aggfin(const float* __restrict__ h, const float* __restrict__ msg,
              const int* __restrict__ off2, const int* __restrict__ eid2,
              const float* __restrict__ invd, const float* __restrict__ rw,
              const float* __restrict__ cb, float* __restrict__ hout) {
    __shared__ float Ws[64 * 64];
    __shared__ float As[4 * 64];
    __shared__ int eoff[5];
    const int tid = threadIdx.x;
    for (int idx = tid; idx < 64 * 64; idx += 256) Ws[idx] = rw[idx];
    const int r0 = blockIdx.x * 4;
    As[tid] = h[(size_t)r0 * 64 + tid];
    if (tid < 5) eoff[tid] = off2[r0 + tid];
    __syncthreads();
    const int rr = tid >> 6, c = tid & 63;
    const int r = r0 + rr;
    float a = 0.f;
    for (int p = eoff[rr]; p < eoff[rr + 1]; ++p) {
        const int e = eid2[p];
        a += msg[(size_t)e * 64 + c];
    }
    float s = cb[c] + a * invd[r];
#pragma unroll
    for (int k = 0; k < 64; k++) s += As[rr * 64 + k] * Ws[k * 64 + c];
    hout[(size_t)r * 64 + c] = silu_f(s);
}

// ---------------- global mean pool (accumulate) ----------------
__global__ void k_pool(const float* __restrict__ h, const int* __restrict__ batch,
                       float* __restrict__ hg, float* __restrict__ gcnt) {
    int idx = blockIdx.x * 256 + threadIdx.x;
    if (idx >= NN * 64) return;
    int n = idx >> 6, o = idx & 63;
    int b = batch[n];
    atomicAdd(&hg[b * 64 + o], h[idx]);
    if (o == 0) atomicAdd(&gcnt[b], 1.f);
}

// ---------------- head MLP ----------------
__global__ __launch_bounds__(64)
void k_head(const float* __restrict__ hg, const float* __restrict__ gcnt,
            const float* __restrict__ w1, const float* __restrict__ b1,
            const float* __restrict__ w2, const float* __restrict__ b2,
            float* __restrict__ out) {
    __shared__ float hrow[64];
    const int gidx = blockIdx.x, t = threadIdx.x;
    const float inv = 1.f / fmaxf(gcnt[gidx], 1.f);
    hrow[t] = hg[gidx * 64 + t] * inv;
    __syncthreads();
    float s = b1[t];
#pragma unroll
    for (int k = 0; k < 64; k++) s += hrow[k] * w1[k * 64 + t];
    s = silu_f(s);
    float v = s * w2[t];
#pragma unroll
    for (int d = 32; d > 0; d >>= 1) v += __shfl_down(v, d);
    if (t == 0) out[gidx] = v + b2[0];
}

extern "C" void kernel_launch(void* const* d_in, const int* in_sizes, int n_in,
                              void* d_out, int out_size, void* d_ws, size_t ws_size,
                              hipStream_t stream) {
    const float* x     = (const float*)d_in[0];
    const float* ea    = (const float*)d_in[1];
    const int*   ei    = (const int*)  d_in[2];
    const int*   batch = (const int*)  d_in[3];
    const float* pw    = (const float*)d_in[4];
    const float* pb    = (const float*)d_in[5];
    const float* ew1   = (const float*)d_in[6];
    const float* eb1   = (const float*)d_in[7];
    const float* ew2   = (const float*)d_in[8];
    const float* eb2   = (const float*)d_in[9];
    const float* rw    = (const float*)d_in[10];
    const float* cb    = (const float*)d_in[11];
    const float* hw1   = (const float*)d_in[12];
    const float* hb1   = (const float*)d_in[13];
    const float* hw2   = (const float*)d_in[14];
    const float* hb2   = (const float*)d_in[15];
    float* out = (float*)d_out;

    float* ws = (float*)d_ws;
    size_t off = 0;
    auto alloc = [&](size_t n) {
        float* p = ws + off;
        off += (n + 63) & ~(size_t)63;
        return p;
    };
    float* hA   = alloc((size_t)NN * 64);
    float* hBuf = alloc((size_t)NN * 64);
    float* gbuf = alloc((size_t)NE * 64);
    float* Cbuf = alloc((size_t)NN * 64);
    float* msg  = alloc((size_t)NE * 64);
    float* invd = alloc(NN);
    float* hg   = alloc(64 * 64);
    float* gcnt = alloc(64);
    int* off_s = (int*)alloc(NN + 1);
    int* off_d = (int*)alloc(NN + 1);
    int* cnt_s = (int*)alloc(NN);
    int* cnt_d = (int*)alloc(NN);
    int* cur_s = (int*)alloc(NN);
    int* cur_d = (int*)alloc(NN);
    int* eid_s = (int*)alloc(NE);
    int* eid_d = (int*)alloc(NE);

    hipMemsetAsync(cnt_s, 0, NN * sizeof(int), stream);
    hipMemsetAsync(cnt_d, 0, NN * sizeof(int), stream);
    hipMemsetAsync(hg, 0, 64 * 64 * sizeof(float), stream);
    hipMemsetAsync(gcnt, 0, 64 * sizeof(float), stream);

    k_hist<<<dim3((NE + 255) / 256), dim3(256), 0, stream>>>(ei, cnt_s, cnt_d);
    k_invdeg<<<dim3((NN + 255) / 256), dim3(256), 0, stream>>>(cnt_d, invd);
    k_scan<<<dim3(1), dim3(1024), 0, stream>>>(cnt_s, off_s, cur_s);
    k_scan<<<dim3(1), dim3(1024), 0, stream>>>(cnt_d, off_d, cur_d);
    k_fill<<<dim3((NE + 255) / 256), dim3(256), 0, stream>>>(ei, off_s, cur_s, eid_s);
    k_fill<<<dim3((NE + 255) / 256), dim3(256), 0, stream>>>(ei + NE, off_d, cur_d, eid_d);

    // h = x @ proj_w + proj_b
    k_rowmm<64, false, true><<<dim3(NN / 4), dim3(256), 0, stream>>>(x, pw, pb, hA, NN);

    const size_t MSG_LDS_BYTES = (size_t)MSG_LDS_FLOATS * sizeof(float);
    hipFuncSetAttribute(reinterpret_cast<const void*>(k_msg),
                        hipFuncAttributeMaxDynamicSharedMemorySize, (int)MSG_LDS_BYTES);

    float* hcur = hA;
    float* hnxt = hBuf;
    for (int l = 0; l < NLAYERS; l++) {
        // g = silu(edge_attr @ w1 + b1)
        k_rowmm<16, true, true><<<dim3(NE / 4), dim3(256), 0, stream>>>(
            ea, ew1 + (size_t)l * EDIM * 64, eb1 + (size_t)l * 64, gbuf, NE);
        // C = h @ b2(reshaped 64x64)
        k_rowmm<64, false, false><<<dim3(NN / 4), dim3(256), 0, stream>>>(
            hcur, eb2 + (size_t)l * 4096, nullptr, Cbuf, NN);
        k_msg<<<dim3(NGROUPS * 2), dim3(MSG_THREADS), MSG_LDS_BYTES, stream>>>(
            hcur, gbuf, ew2 + (size_t)l * 64 * 4096, Cbuf, off_s, eid_s, msg);
        k_aggfin<<<dim3(NN / 4), dim3(256), 0, stream>>>(
            hcur, msg, off_d, eid_d, invd, rw + (size_t)l * 64 * 64,
            cb + (size_t)l * 64, hnxt);
        float* t = hcur; hcur = hnxt; hnxt = t;
    }

    k_pool<<<dim3((NN * 64) / 256), dim3(256), 0, stream>>>(hcur, batch, hg, gcnt);
    k_head<<<dim3(NGRAPH), dim3(64), 0, stream>>>(hg, gcnt, hw1, hb1, hw2, hb2, out);
}

// Round 4
// 1356.520 us; speedup vs baseline: 1.6092x; 1.6092x over previous
//
#include <hip/hip_runtime.h>
#include <math.h>

#define NN 10000
#define NE 40000
#define NGRAPH 64
#define HID 64
#define EDIM 16
#define NLAYERS 3

// ---- fused message kernel geometry ----
#define GNODES 16
#define NGROUPS (NN / GNODES)       // 625
#define OSUB 16                     // o-slice per block (4 slices)
#define NSLICE 4
#define MSG_THREADS 1024
#define HSTR 20                     // h_s row stride (floats), 16B-aligned float4s, bank-spread
#define B_FLOATS (GNODES * 64 * OSUB)   // 16384 floats = 64 KB
#define HS_FLOATS (64 * HSTR)           // 1280 floats
#define MSG_LDS_FLOATS (B_FLOATS + HS_FLOATS)

__device__ __forceinline__ float silu_f(float x) { return x / (1.f + expf(-x)); }

// ---------------- small row GEMM: out[M][64] = act(A[M][K] @ W[K][64] + bias) ----
template<int K, bool DO_SILU, bool HAS_BIAS>
__global__ __launch_bounds__(256)
void k_rowmm(const float* __restrict__ A, const float* __restrict__ W,
             const float* __restrict__ bias, float* __restrict__ out, int M) {
    __shared__ float Ws[K * 64];
    __shared__ float As[4 * K];
    const int tid = threadIdx.x;
    for (int idx = tid; idx < K * 64; idx += 256) Ws[idx] = W[idx];
    const int r0 = blockIdx.x * 4;
    for (int idx = tid; idx < 4 * K; idx += 256) {
        int r = r0 + idx / K;
        As[idx] = (r < M) ? A[(size_t)r * K + (idx % K)] : 0.f;
    }
    __syncthreads();
    const int rr = tid >> 6, c = tid & 63;
    const int r = r0 + rr;
    if (r >= M) return;
    float s = HAS_BIAS ? bias[c] : 0.f;
#pragma unroll
    for (int k = 0; k < K; k++) s += As[rr * K + k] * Ws[k * 64 + c];
    if (DO_SILU) s = silu_f(s);
    out[(size_t)r * 64 + c] = s;
}

// ---------------- degree histograms (src + dst) ----------------
__global__ void k_hist(const int* __restrict__ ei, int* __restrict__ cnt_s,
                       int* __restrict__ cnt_d) {
    int e = blockIdx.x * 256 + threadIdx.x;
    if (e >= NE) return;
    atomicAdd(&cnt_s[ei[e]], 1);
    atomicAdd(&cnt_d[ei[NE + e]], 1);
}

__global__ void k_invdeg(const int* __restrict__ cnt_d, float* __restrict__ invd) {
    int n = blockIdx.x * 256 + threadIdx.x;
    if (n < NN) {
        int d = cnt_d[n];
        invd[n] = (d > 0) ? 1.f / (float)d : 0.f;
    }
}

// ---------------- single-block exclusive scan over NN counts ----------------
__global__ __launch_bounds__(1024)
void k_scan(const int* __restrict__ cnt, int* __restrict__ off, int* __restrict__ cur) {
    __shared__ int part[1024];
    const int t = threadIdx.x;
    const int CH = (NN + 1023) / 1024;  // 10
    const int base0 = t * CH;
    int s = 0;
    for (int i = 0; i < CH; i++) {
        int idx = base0 + i;
        if (idx < NN) s += cnt[idx];
    }
    part[t] = s;
    __syncthreads();
    for (int d = 1; d < 1024; d <<= 1) {
        int v = (t >= d) ? part[t - d] : 0;
        __syncthreads();
        part[t] += v;
        __syncthreads();
    }
    int run = (t == 0) ? 0 : part[t - 1];
    for (int i = 0; i < CH; i++) {
        int idx = base0 + i;
        if (idx < NN) {
            off[idx] = run;
            run += cnt[idx];
            cur[idx] = 0;
        }
    }
    if (t == 1023) off[NN] = run;
}

__global__ void k_fill(const int* __restrict__ keys, const int* __restrict__ off,
                       int* __restrict__ cur, int* __restrict__ eid) {
    int e = blockIdx.x * 256 + threadIdx.x;
    if (e >= NE) return;
    int s = keys[e];
    int p = atomicAdd(&cur[s], 1);
    eid[off[s] + p] = e;
}

// ---------------- fused B-compute + C-compute + message store (v4) ----------------
// Block = (group of 16 src nodes) x (o-slice of 16). Thread = (k, o-quad, j-quad).
// Accumulators are named float4s -> guaranteed registers (v3 spilled at VGPR=48).
__global__ __launch_bounds__(MSG_THREADS, 8)
void k_msg(const float* __restrict__ h, const float* __restrict__ g,
           const float* __restrict__ w2, const float* __restrict__ b2,
           const int* __restrict__ csr_off, const int* __restrict__ csr_eid,
           float* __restrict__ msg) {
    extern __shared__ float lds[];
    float* Bl  = lds;               // [16 j][64 k][16 o] float4-swizzled by j&3
    float* h_s = lds + B_FLOATS;    // [64 i][stride 20]: h_s[i*20+j] = h[n0+j][i]
    __shared__ float C_s[GNODES * OSUB];   // [16 j][16 ol]
    __shared__ int offs[GNODES + 1];

    const int tid   = threadIdx.x;
    const int slice = blockIdx.x & (NSLICE - 1);
    const int grp   = blockIdx.x >> 2;
    const int o0    = slice * OSUB;
    const int n0    = grp * GNODES;

    // stage h transposed: wave w loads row n0+w coalesced, writes column w
    {
        const int j = tid >> 6, i = tid & 63;
        h_s[i * HSTR + j] = h[(size_t)(n0 + j) * 64 + i];
    }
    if (tid <= GNODES) offs[tid] = csr_off[n0 + tid];
    __syncthreads();

    // C_s[j][ol] = sum_i h[n0+j][i] * b2[i*64 + o0+ol]   (fused Cbuf)
    if (tid < GNODES * OSUB) {
        const int j = tid >> 4, ol = tid & 15;
        const float* bp = b2 + o0 + ol;
        float c = 0.f;
#pragma unroll 8
        for (int i = 0; i < 64; ++i) c += h_s[i * HSTR + j] * bp[i * 64];
        C_s[tid] = c;
    }

    // ---- B compute: thread (k = tid>>4, oq = (tid>>2)&3, jq = tid&3) ----
    const int k  = tid >> 4;
    const int oq = (tid >> 2) & 3;
    const int jq = tid & 3;
    const float* w2p = w2 + (size_t)k * 4096 + o0 + oq * 4;
    const float* hp  = h_s + jq * 4;

    float4 a0 = {0.f, 0.f, 0.f, 0.f};
    float4 a1 = {0.f, 0.f, 0.f, 0.f};
    float4 a2 = {0.f, 0.f, 0.f, 0.f};
    float4 a3 = {0.f, 0.f, 0.f, 0.f};
#pragma unroll 4
    for (int i = 0; i < 64; ++i) {
        const float4 wv = *(const float4*)(w2p + i * 64);
        const float4 hv = *(const float4*)(hp + i * HSTR);
        a0.x += hv.x * wv.x; a0.y += hv.x * wv.y; a0.z += hv.x * wv.z; a0.w += hv.x * wv.w;
        a1.x += hv.y * wv.x; a1.y += hv.y * wv.y; a1.z += hv.y * wv.z; a1.w += hv.y * wv.w;
        a2.x += hv.z * wv.x; a2.y += hv.z * wv.y; a2.z += hv.z * wv.z; a2.w += hv.z * wv.w;
        a3.x += hv.w * wv.x; a3.y += hv.w * wv.y; a3.z += hv.w * wv.z; a3.w += hv.w * wv.w;
    }
    // write B: float4 index (j, k, oq') = j*256 + k*4 + (oq ^ (j&3));  j = jq*4+jj
    {
        float4* Bl4 = (float4*)Bl;
        Bl4[(jq * 4 + 0) * 256 + k * 4 + (oq ^ 0)] = a0;
        Bl4[(jq * 4 + 1) * 256 + k * 4 + (oq ^ 1)] = a1;
        Bl4[(jq * 4 + 2) * 256 + k * 4 + (oq ^ 2)] = a2;
        Bl4[(jq * 4 + 3) * 256 + k * 4 + (oq ^ 3)] = a3;
    }
    __syncthreads();

    // ---- edge phase: task = (edge slot) x (o-quad of 4) ----
    const float4* Bl4 = (const float4*)Bl;
    const float4* C_s4 = (const float4*)C_s;
    const int P0 = offs[0];
    const int Etot = offs[GNODES] - P0;
    const int ntask = Etot * 4;
    for (int t = tid; t < ntask; t += MSG_THREADS) {
        const int slot = t >> 2, oq2 = t & 3;
        const int gpos = P0 + slot;
        int j = 0;
#pragma unroll
        for (int q = 1; q < GNODES; ++q) j += (gpos >= offs[q]) ? 1 : 0;
        const int e = csr_eid[gpos];
        const float* grow = g + (size_t)e * 64;
        const int jbase = j * 256;
        const int sw = oq2 ^ (j & 3);

        float4 c4 = C_s4[j * 4 + oq2];
        float m0 = c4.x, m1 = c4.y, m2 = c4.z, m3 = c4.w;
#pragma unroll
        for (int k8 = 0; k8 < 8; ++k8) {
            const float4 ga = *(const float4*)(grow + k8 * 8);
            const float4 gb = *(const float4*)(grow + k8 * 8 + 4);
#define FMA4(GK, KK) { \
            const float4 b4 = Bl4[jbase + (k8 * 8 + KK) * 4 + sw]; \
            m0 += (GK) * b4.x; m1 += (GK) * b4.y; m2 += (GK) * b4.z; m3 += (GK) * b4.w; }
            FMA4(ga.x, 0) FMA4(ga.y, 1) FMA4(ga.z, 2) FMA4(ga.w, 3)
            FMA4(gb.x, 4) FMA4(gb.y, 5) FMA4(gb.z, 6) FMA4(gb.w, 7)
#undef FMA4
        }
        *(float4*)(msg + (size_t)e * 64 + o0 + oq2 * 4) = make_float4(m0, m1, m2, m3);
    }
}

// ---------------- gather by dst + root GEMM + silu ----------------
__global__ __launch_bounds__(256)
void k_aggfin(const float* __restrict__ h, const float* __restrict__ msg,
              const int* __restrict__ off2, const int* __restrict__ eid2,
              const float* __restrict__ invd, const float* __restrict__ rw,
              const float* __restrict__ cb, float* __restrict__ hout) {
    __shared__ float Ws[64 * 64];
    __shared__ float As[4 * 64];
    __shared__ int eoff[5];
    const int tid = threadIdx.x;
    for (int idx = tid; idx < 64 * 64; idx += 256) Ws[idx] = rw[idx];
    const int r0 = blockIdx.x * 4;
    As[tid] = h[(size_t)r0 * 64 + tid];
    if (tid < 5) eoff[tid] = off2[r0 + tid];
    __syncthreads();
    const int rr = tid >> 6, c = tid & 63;
    const int r = r0 + rr;
    float a = 0.f;
    for (int p = eoff[rr]; p < eoff[rr + 1]; ++p) {
        const int e = eid2[p];
        a += msg[(size_t)e * 64 + c];
    }
    float s = cb[c] + a * invd[r];
#pragma unroll
    for (int k = 0; k < 64; k++) s += As[rr * 64 + k] * Ws[k * 64 + c];
    hout[(size_t)r * 64 + c] = silu_f(s);
}

// ---------------- global mean pool (accumulate) ----------------
__global__ void k_pool(const float* __restrict__ h, const int* __restrict__ batch,
                       float* __restrict__ hg, float* __restrict__ gcnt) {
    int idx = blockIdx.x * 256 + threadIdx.x;
    if (idx >= NN * 64) return;
    int n = idx >> 6, o = idx & 63;
    int b = batch[n];
    atomicAdd(&hg[b * 64 + o], h[idx]);
    if (o == 0) atomicAdd(&gcnt[b], 1.f);
}

// ---------------- head MLP ----------------
__global__ __launch_bounds__(64)
void k_head(const float* __restrict__ hg, const float* __restrict__ gcnt,
            const float* __restrict__ w1, const float* __restrict__ b1,
            const float* __restrict__ w2, const float* __restrict__ b2,
            float* __restrict__ out) {
    __shared__ float hrow[64];
    const int gidx = blockIdx.x, t = threadIdx.x;
    const float inv = 1.f / fmaxf(gcnt[gidx], 1.f);
    hrow[t] = hg[gidx * 64 + t] * inv;
    __syncthreads();
    float s = b1[t];
#pragma unroll
    for (int k = 0; k < 64; k++) s += hrow[k] * w1[k * 64 + t];
    s = silu_f(s);
    float v = s * w2[t];
#pragma unroll
    for (int d = 32; d > 0; d >>= 1) v += __shfl_down(v, d);
    if (t == 0) out[gidx] = v + b2[0];
}

extern "C" void kernel_launch(void* const* d_in, const int* in_sizes, int n_in,
                              void* d_out, int out_size, void* d_ws, size_t ws_size,
                              hipStream_t stream) {
    const float* x     = (const float*)d_in[0];
    const float* ea    = (const float*)d_in[1];
    const int*   ei    = (const int*)  d_in[2];
    const int*   batch = (const int*)  d_in[3];
    const float* pw    = (const float*)d_in[4];
    const float* pb    = (const float*)d_in[5];
    const float* ew1   = (const float*)d_in[6];
    const float* eb1   = (const float*)d_in[7];
    const float* ew2   = (const float*)d_in[8];
    const float* eb2   = (const float*)d_in[9];
    const float* rw    = (const float*)d_in[10];
    const float* cb    = (const float*)d_in[11];
    const float* hw1   = (const float*)d_in[12];
    const float* hb1   = (const float*)d_in[13];
    const float* hw2   = (const float*)d_in[14];
    const float* hb2   = (const float*)d_in[15];
    float* out = (float*)d_out;

    float* ws = (float*)d_ws;
    size_t off = 0;
    auto alloc = [&](size_t n) {
        float* p = ws + off;
        off += (n + 63) & ~(size_t)63;
        return p;
    };
    float* hA   = alloc((size_t)NN * 64);
    float* hBuf = alloc((size_t)NN * 64);
    float* gbuf = alloc((size_t)NE * 64);
    float* msg  = alloc((size_t)NE * 64);
    float* invd = alloc(NN);
    float* hg   = alloc(64 * 64);
    float* gcnt = alloc(64);
    int* off_s = (int*)alloc(NN + 1);
    int* off_d = (int*)alloc(NN + 1);
    int* cnt_s = (int*)alloc(NN);
    int* cnt_d = (int*)alloc(NN);
    int* cur_s = (int*)alloc(NN);
    int* cur_d = (int*)alloc(NN);
    int* eid_s = (int*)alloc(NE);
    int* eid_d = (int*)alloc(NE);

    hipMemsetAsync(cnt_s, 0, NN * sizeof(int), stream);
    hipMemsetAsync(cnt_d, 0, NN * sizeof(int), stream);
    hipMemsetAsync(hg, 0, 64 * 64 * sizeof(float), stream);
    hipMemsetAsync(gcnt, 0, 64 * sizeof(float), stream);

    k_hist<<<dim3((NE + 255) / 256), dim3(256), 0, stream>>>(ei, cnt_s, cnt_d);
    k_invdeg<<<dim3((NN + 255) / 256), dim3(256), 0, stream>>>(cnt_d, invd);
    k_scan<<<dim3(1), dim3(1024), 0, stream>>>(cnt_s, off_s, cur_s);
    k_scan<<<dim3(1), dim3(1024), 0, stream>>>(cnt_d, off_d, cur_d);
    k_fill<<<dim3((NE + 255) / 256), dim3(256), 0, stream>>>(ei, off_s, cur_s, eid_s);
    k_fill<<<dim3((NE + 255) / 256), dim3(256), 0, stream>>>(ei + NE, off_d, cur_d, eid_d);

    // h = x @ proj_w + proj_b
    k_rowmm<64, false, true><<<dim3(NN / 4), dim3(256), 0, stream>>>(x, pw, pb, hA, NN);

    const size_t MSG_LDS_BYTES = (size_t)MSG_LDS_FLOATS * sizeof(float);
    hipFuncSetAttribute(reinterpret_cast<const void*>(k_msg),
                        hipFuncAttributeMaxDynamicSharedMemorySize, (int)MSG_LDS_BYTES);

    float* hcur = hA;
    float* hnxt = hBuf;
    for (int l = 0; l < NLAYERS; l++) {
        // g = silu(edge_attr @ w1 + b1)
        k_rowmm<16, true, true><<<dim3(NE / 4), dim3(256), 0, stream>>>(
            ea, ew1 + (size_t)l * EDIM * 64, eb1 + (size_t)l * 64, gbuf, NE);
        k_msg<<<dim3(NGROUPS * NSLICE), dim3(MSG_THREADS), MSG_LDS_BYTES, stream>>>(
            hcur, gbuf, ew2 + (size_t)l * 64 * 4096, eb2 + (size_t)l * 4096,
            off_s, eid_s, msg);
        k_aggfin<<<dim3(NN / 4), dim3(256), 0, stream>>>(
            hcur, msg, off_d, eid_d, invd, rw + (size_t)l * 64 * 64,
            cb + (size_t)l * 64, hnxt);
        float* t = hcur; hcur = hnxt; hnxt = t;
    }

    k_pool<<<dim3((NN * 64) / 256), dim3(256), 0, stream>>>(hcur, batch, hg, gcnt);
    k_head<<<dim3(NGRAPH), dim3(64), 0, stream>>>(hg, gcnt, hw1, hb1, hw2, hb2, out);
}

// Round 5
// 1353.493 us; speedup vs baseline: 1.6128x; 1.0022x over previous
//
#include <hip/hip_runtime.h>
#include <math.h>

#define NN 10000
#define NE 40000
#define NGRAPH 64
#define HID 64
#define EDIM 16
#define NLAYERS 3

// ---- fused message kernel geometry (v5: o-dense, no slicing) ----
#define GNODES 8
#define NGROUPS (NN / GNODES)       // 1250
#define MSG_THREADS 1024            // 16 waves, 1 block/CU (136KB LDS)
#define HSTR 12                     // h_s row stride: float4-aligned, bank-spread
#define B_FLOATS (GNODES * 64 * 64) // 32768 floats = 128 KB
#define HS_FLOATS (64 * HSTR)       // 768
#define CS_FLOATS (GNODES * 64)     // 512
#define MSG_LDS_FLOATS (B_FLOATS + HS_FLOATS + CS_FLOATS)   // 34048 = 136192 B

__device__ __forceinline__ float silu_f(float x) { return x / (1.f + expf(-x)); }

// ---------------- small row GEMM: out[M][64] = act(A[M][K] @ W[K][64] + bias) ----
template<int K, bool DO_SILU, bool HAS_BIAS>
__global__ __launch_bounds__(256)
void k_rowmm(const float* __restrict__ A, const float* __restrict__ W,
             const float* __restrict__ bias, float* __restrict__ out, int M) {
    __shared__ float Ws[K * 64];
    __shared__ float As[4 * K];
    const int tid = threadIdx.x;
    for (int idx = tid; idx < K * 64; idx += 256) Ws[idx] = W[idx];
    const int r0 = blockIdx.x * 4;
    for (int idx = tid; idx < 4 * K; idx += 256) {
        int r = r0 + idx / K;
        As[idx] = (r < M) ? A[(size_t)r * K + (idx % K)] : 0.f;
    }
    __syncthreads();
    const int rr = tid >> 6, c = tid & 63;
    const int r = r0 + rr;
    if (r >= M) return;
    float s = HAS_BIAS ? bias[c] : 0.f;
#pragma unroll
    for (int k = 0; k < K; k++) s += As[rr * K + k] * Ws[k * 64 + c];
    if (DO_SILU) s = silu_f(s);
    out[(size_t)r * 64 + c] = s;
}

// ---------------- degree histograms (src + dst) ----------------
__global__ void k_hist(const int* __restrict__ ei, int* __restrict__ cnt_s,
                       int* __restrict__ cnt_d) {
    int e = blockIdx.x * 256 + threadIdx.x;
    if (e >= NE) return;
    atomicAdd(&cnt_s[ei[e]], 1);
    atomicAdd(&cnt_d[ei[NE + e]], 1);
}

__global__ void k_invdeg(const int* __restrict__ cnt_d, float* __restrict__ invd) {
    int n = blockIdx.x * 256 + threadIdx.x;
    if (n < NN) {
        int d = cnt_d[n];
        invd[n] = (d > 0) ? 1.f / (float)d : 0.f;
    }
}

// ---------------- single-block exclusive scan over NN counts ----------------
__global__ __launch_bounds__(1024)
void k_scan(const int* __restrict__ cnt, int* __restrict__ off, int* __restrict__ cur) {
    __shared__ int part[1024];
    const int t = threadIdx.x;
    const int CH = (NN + 1023) / 1024;  // 10
    const int base0 = t * CH;
    int s = 0;
    for (int i = 0; i < CH; i++) {
        int idx = base0 + i;
        if (idx < NN) s += cnt[idx];
    }
    part[t] = s;
    __syncthreads();
    for (int d = 1; d < 1024; d <<= 1) {
        int v = (t >= d) ? part[t - d] : 0;
        __syncthreads();
        part[t] += v;
        __syncthreads();
    }
    int run = (t == 0) ? 0 : part[t - 1];
    for (int i = 0; i < CH; i++) {
        int idx = base0 + i;
        if (idx < NN) {
            off[idx] = run;
            run += cnt[idx];
            cur[idx] = 0;
        }
    }
    if (t == 1023) off[NN] = run;
}

__global__ void k_fill(const int* __restrict__ keys, const int* __restrict__ off,
                       int* __restrict__ cur, int* __restrict__ eid) {
    int e = blockIdx.x * 256 + threadIdx.x;
    if (e >= NE) return;
    int s = keys[e];
    int p = atomicAdd(&cur[s], 1);
    eid[off[s] + p] = e;
}

// ---------------- fused B-compute + C-compute + message store (v5) ----------------
// Block = group of 8 src nodes, FULL o=64 (lanes map to o -> every w2/b2/msg
// access is a dense 256B wave transaction; w2 read exactly once per block).
__global__ __launch_bounds__(MSG_THREADS, 4)
void k_msg(const float* __restrict__ h, const float* __restrict__ g,
           const float* __restrict__ w2, const float* __restrict__ b2,
           const int* __restrict__ csr_off, const int* __restrict__ csr_eid,
           float* __restrict__ msg) {
    extern __shared__ float lds[];
    float* Bl  = lds;                         // [8 j][64 k][64 o] linear
    float* h_s = lds + B_FLOATS;              // [64 i][stride 12]
    float* C_s = lds + B_FLOATS + HS_FLOATS;  // [8 j][64 o]
    __shared__ int offs[GNODES + 1];

    const int tid = threadIdx.x;
    const int n0  = blockIdx.x * GNODES;
    const int o   = tid & 63;
    const int kc  = tid >> 6;     // 0..15

    // stage h transposed: wave j loads row n0+j coalesced (256B), writes col j
    if (tid < GNODES * 64) {
        const int j = tid >> 6, i = tid & 63;
        h_s[i * HSTR + j] = h[(size_t)(n0 + j) * 64 + i];
    }
    if (tid <= GNODES) offs[tid] = csr_off[n0 + tid];
    __syncthreads();

    // ---- C phase (512 threads): C_s[j][o] = sum_i h[j,i] * b2[i*64+o] ----
    if (tid < GNODES * 64) {
        const int j = tid >> 6;
        const float* bp = b2 + o;
        float c = 0.f;
#pragma unroll 8
        for (int i = 0; i < 64; ++i) c += h_s[i * HSTR + j] * bp[i * 64];
        C_s[j * 64 + o] = c;
    }

    // ---- B phase: thread (kc, o) owns k = kc*4+kk, all 8 j ----
    // w2 loads: 64 lanes x 4B contiguous (dense 256B), 4 sequential streams.
    {
        const float* w2p = w2 + (size_t)kc * 4 * 4096 + o;
        float acc[4][8];
#pragma unroll
        for (int kk = 0; kk < 4; ++kk)
#pragma unroll
            for (int j = 0; j < 8; ++j) acc[kk][j] = 0.f;

        float wc[4], wn[4];
#pragma unroll
        for (int kk = 0; kk < 4; ++kk) wc[kk] = w2p[kk * 4096];

#pragma unroll 4
        for (int i = 0; i < 64; ++i) {
            const int ip = (i + 1) & 63;   // branch-free prefetch (wraps once)
#pragma unroll
            for (int kk = 0; kk < 4; ++kk) wn[kk] = w2p[kk * 4096 + ip * 64];
            const float4 ha = *(const float4*)(h_s + i * HSTR);
            const float4 hb = *(const float4*)(h_s + i * HSTR + 4);
#pragma unroll
            for (int kk = 0; kk < 4; ++kk) {
                const float w = wc[kk];
                acc[kk][0] += w * ha.x; acc[kk][1] += w * ha.y;
                acc[kk][2] += w * ha.z; acc[kk][3] += w * ha.w;
                acc[kk][4] += w * hb.x; acc[kk][5] += w * hb.y;
                acc[kk][6] += w * hb.z; acc[kk][7] += w * hb.w;
            }
#pragma unroll
            for (int kk = 0; kk < 4; ++kk) wc[kk] = wn[kk];
        }
        // write B: lanes o stride-1 -> conflict-free
#pragma unroll
        for (int kk = 0; kk < 4; ++kk) {
            const int k = kc * 4 + kk;
#pragma unroll
            for (int j = 0; j < 8; ++j)
                Bl[j * 4096 + k * 64 + o] = acc[kk][j];
        }
    }
    __syncthreads();

    // ---- edge phase: task = (edge slot) x (o4 of 16B); 64 slots/pass ----
    const float4* Bl4 = (const float4*)Bl;
    const float4* Cs4 = (const float4*)C_s;
    const int P0 = offs[0];
    const int Etot = offs[GNODES] - P0;
    const int o4 = tid & 15;
    for (int slot = tid >> 4; slot < Etot; slot += 64) {
        const int gpos = P0 + slot;
        int j = 0;
#pragma unroll
        for (int q = 1; q < GNODES; ++q) j += (gpos >= offs[q]) ? 1 : 0;
        const int e = csr_eid[gpos];
        const float* grow = g + (size_t)e * 64;
        const float4* BjRow = Bl4 + j * 1024 + o4;   // (j*4096 + k*64)/4 + o4

        float4 m0 = Cs4[j * 16 + o4];
        float4 m1 = {0.f, 0.f, 0.f, 0.f};
#pragma unroll
        for (int k4 = 0; k4 < 16; ++k4) {
            const float4 g4 = *(const float4*)(grow + k4 * 4);  // wave-broadcast
            const float4 b0 = BjRow[(k4 * 4 + 0) * 16];
            const float4 b1 = BjRow[(k4 * 4 + 1) * 16];
            const float4 b2v = BjRow[(k4 * 4 + 2) * 16];
            const float4 b3 = BjRow[(k4 * 4 + 3) * 16];
            m0.x += g4.x * b0.x; m0.y += g4.x * b0.y; m0.z += g4.x * b0.z; m0.w += g4.x * b0.w;
            m1.x += g4.y * b1.x; m1.y += g4.y * b1.y; m1.z += g4.y * b1.z; m1.w += g4.y * b1.w;
            m0.x += g4.z * b2v.x; m0.y += g4.z * b2v.y; m0.z += g4.z * b2v.z; m0.w += g4.z * b2v.w;
            m1.x += g4.w * b3.x; m1.y += g4.w * b3.y; m1.z += g4.w * b3.z; m1.w += g4.w * b3.w;
        }
        const float4 m = make_float4(m0.x + m1.x, m0.y + m1.y, m0.z + m1.z, m0.w + m1.w);
        *(float4*)(msg + (size_t)e * 64 + o4 * 4) = m;
    }
}

// ---------------- gather by dst + root GEMM + silu ----------------
__global__ __launch_bounds__(256)
void k_aggfin(const float* __restrict__ h, const float* __restrict__ msg,
              const int* __restrict__ off2, const int* __restrict__ eid2,
              const float* __restrict__ invd, const float* __restrict__ rw,
              const float* __restrict__ cb, float* __restrict__ hout) {
    __shared__ float Ws[64 * 64];
    __shared__ float As[4 * 64];
    __shared__ int eoff[5];
    const int tid = threadIdx.x;
    for (int idx = tid; idx < 64 * 64; idx += 256) Ws[idx] = rw[idx];
    const int r0 = blockIdx.x * 4;
    As[tid] = h[(size_t)r0 * 64 + tid];
    if (tid < 5) eoff[tid] = off2[r0 + tid];
    __syncthreads();
    const int rr = tid >> 6, c = tid & 63;
    const int r = r0 + rr;
    float a = 0.f;
    for (int p = eoff[rr]; p < eoff[rr + 1]; ++p) {
        const int e = eid2[p];
        a += msg[(size_t)e * 64 + c];
    }
    float s = cb[c] + a * invd[r];
#pragma unroll
    for (int k = 0; k < 64; k++) s += As[rr * 64 + k] * Ws[k * 64 + c];
    hout[(size_t)r * 64 + c] = silu_f(s);
}

// ---------------- global mean pool (accumulate) ----------------
__global__ void k_pool(const float* __restrict__ h, const int* __restrict__ batch,
                       float* __restrict__ hg, float* __restrict__ gcnt) {
    int idx = blockIdx.x * 256 + threadIdx.x;
    if (idx >= NN * 64) return;
    int n = idx >> 6, o = idx & 63;
    int b = batch[n];
    atomicAdd(&hg[b * 64 + o], h[idx]);
    if (o == 0) atomicAdd(&gcnt[b], 1.f);
}

// ---------------- head MLP ----------------
__global__ __launch_bounds__(64)
void k_head(const float* __restrict__ hg, const float* __restrict__ gcnt,
            const float* __restrict__ w1, const float* __restrict__ b1,
            const float* __restrict__ w2, const float* __restrict__ b2,
            float* __restrict__ out) {
    __shared__ float hrow[64];
    const int gidx = blockIdx.x, t = threadIdx.x;
    const float inv = 1.f / fmaxf(gcnt[gidx], 1.f);
    hrow[t] = hg[gidx * 64 + t] * inv;
    __syncthreads();
    float s = b1[t];
#pragma unroll
    for (int k = 0; k < 64; k++) s += hrow[k] * w1[k * 64 + t];
    s = silu_f(s);
    float v = s * w2[t];
#pragma unroll
    for (int d = 32; d > 0; d >>= 1) v += __shfl_down(v, d);
    if (t == 0) out[gidx] = v + b2[0];
}

extern "C" void kernel_launch(void* const* d_in, const int* in_sizes, int n_in,
                              void* d_out, int out_size, void* d_ws, size_t ws_size,
                              hipStream_t stream) {
    const float* x     = (const float*)d_in[0];
    const float* ea    = (const float*)d_in[1];
    const int*   ei    = (const int*)  d_in[2];
    const int*   batch = (const int*)  d_in[3];
    const float* pw    = (const float*)d_in[4];
    const float* pb    = (const float*)d_in[5];
    const float* ew1   = (const float*)d_in[6];
    const float* eb1   = (const float*)d_in[7];
    const float* ew2   = (const float*)d_in[8];
    const float* eb2   = (const float*)d_in[9];
    const float* rw    = (const float*)d_in[10];
    const float* cb    = (const float*)d_in[11];
    const float* hw1   = (const float*)d_in[12];
    const float* hb1   = (const float*)d_in[13];
    const float* hw2   = (const float*)d_in[14];
    const float* hb2   = (const float*)d_in[15];
    float* out = (float*)d_out;

    float* ws = (float*)d_ws;
    size_t off = 0;
    auto alloc = [&](size_t n) {
        float* p = ws + off;
        off += (n + 63) & ~(size_t)63;
        return p;
    };
    float* hA   = alloc((size_t)NN * 64);
    float* hBuf = alloc((size_t)NN * 64);
    float* gbuf = alloc((size_t)NE * 64);
    float* msg  = alloc((size_t)NE * 64);
    float* invd = alloc(NN);
    float* hg   = alloc(64 * 64);
    float* gcnt = alloc(64);
    int* off_s = (int*)alloc(NN + 1);
    int* off_d = (int*)alloc(NN + 1);
    int* cnt_s = (int*)alloc(NN);
    int* cnt_d = (int*)alloc(NN);
    int* cur_s = (int*)alloc(NN);
    int* cur_d = (int*)alloc(NN);
    int* eid_s = (int*)alloc(NE);
    int* eid_d = (int*)alloc(NE);

    hipMemsetAsync(cnt_s, 0, NN * sizeof(int), stream);
    hipMemsetAsync(cnt_d, 0, NN * sizeof(int), stream);
    hipMemsetAsync(hg, 0, 64 * 64 * sizeof(float), stream);
    hipMemsetAsync(gcnt, 0, 64 * sizeof(float), stream);

    k_hist<<<dim3((NE + 255) / 256), dim3(256), 0, stream>>>(ei, cnt_s, cnt_d);
    k_invdeg<<<dim3((NN + 255) / 256), dim3(256), 0, stream>>>(cnt_d, invd);
    k_scan<<<dim3(1), dim3(1024), 0, stream>>>(cnt_s, off_s, cur_s);
    k_scan<<<dim3(1), dim3(1024), 0, stream>>>(cnt_d, off_d, cur_d);
    k_fill<<<dim3((NE + 255) / 256), dim3(256), 0, stream>>>(ei, off_s, cur_s, eid_s);
    k_fill<<<dim3((NE + 255) / 256), dim3(256), 0, stream>>>(ei + NE, off_d, cur_d, eid_d);

    // h = x @ proj_w + proj_b
    k_rowmm<64, false, true><<<dim3(NN / 4), dim3(256), 0, stream>>>(x, pw, pb, hA, NN);

    const size_t MSG_LDS_BYTES = (size_t)MSG_LDS_FLOATS * sizeof(float);
    hipFuncSetAttribute(reinterpret_cast<const void*>(k_msg),
                        hipFuncAttributeMaxDynamicSharedMemorySize, (int)MSG_LDS_BYTES);

    float* hcur = hA;
    float* hnxt = hBuf;
    for (int l = 0; l < NLAYERS; l++) {
        // g = silu(edge_attr @ w1 + b1)
        k_rowmm<16, true, true><<<dim3(NE / 4), dim3(256), 0, stream>>>(
            ea, ew1 + (size_t)l * EDIM * 64, eb1 + (size_t)l * 64, gbuf, NE);
        k_msg<<<dim3(NGROUPS), dim3(MSG_THREADS), MSG_LDS_BYTES, stream>>>(
            hcur, gbuf, ew2 + (size_t)l * 64 * 4096, eb2 + (size_t)l * 4096,
            off_s, eid_s, msg);
        k_aggfin<<<dim3(NN / 4), dim3(256), 0, stream>>>(
            hcur, msg, off_d, eid_d, invd, rw + (size_t)l * 64 * 64,
            cb + (size_t)l * 64, hnxt);
        float* t = hcur; hcur = hnxt; hnxt = t;
    }

    k_pool<<<dim3((NN * 64) / 256), dim3(256), 0, stream>>>(hcur, batch, hg, gcnt);
    k_head<<<dim3(NGRAPH), dim3(64), 0, stream>>>(hg, gcnt, hw1, hb1, hw2, hb2, out);
}